// Round 6
// baseline (525.023 us; speedup 1.0000x reference)
//
#include <hip/hip_runtime.h>

#define B 4
#define C 48
#define C3 144
#define H 256
#define W 256
#define HW 65536
#define EPSN 1e-12f

// ---- a1 tiling: 16x12 output tile, 18x14 halo (252 positions) ----
#define TSX 16
#define TSY 12
#define HSX 18
#define HSY 14
#define NTX 16           // 256/16
#define NTY 22           // ceil(256/12)
#define NPIX2 192        // TSX*TSY
#define NHALO 252        // HSX*HSY

#define NCHUNK 64        // gram chunks per batch
#define CHUNK 1024       // pixels per gram chunk

// ================= PATH A workspace layout (floats), ~103 MB =================
#define A_DWQ_OFF  ((size_t)0)
#define A_DWK_OFF  (A_DWQ_OFF + (size_t)B * C * HW)
#define A_SP_OFF   (A_DWK_OFF + (size_t)B * C * HW)            // B*64*2304
#define A_NQP_OFF  (A_SP_OFF + (size_t)B * NCHUNK * C * C)     // B*64*48
#define A_NKP_OFF  (A_NQP_OFF + (size_t)B * NCHUNK * C)
#define A_S_OFF    (A_NKP_OFF + (size_t)B * NCHUNK * C)        // B*2304
#define A_NQ_OFF   (A_S_OFF + (size_t)B * C * C)               // B*48
#define A_NK_OFF   (A_NQ_OFF + (size_t)B * C)
#define A_M_OFF    (A_NK_OFF + (size_t)B * C)                  // B*2304
#define A_FLOATS   (A_M_OFF + (size_t)B * C * C)

// ================= PATH B (fallback) workspace layout, ~75 KB ================
#define B_S_OFF  0
#define B_NQ_OFF (B * C * C)
#define B_NK_OFF (B_NQ_OFF + B * C)
#define B_M_OFF  (B_NK_OFF + B * C)
#define B_ZERO_N (B * C * C + 2 * B * C)

// ============================ PATH A kernels =================================

// A1: 1x1 conv + depthwise 3x3. One block per (batch, 16x12 tile).
// x halo tile staged in LDS (rounds 3-5 proved the register allocator refuses
// to keep a per-thread xv[48] resident: VGPR_Count 40/48/52, loads sunk into
// the group loop, VALUBusy ~28%). LDS xs[ch][pos] is conflict-free
// (lane-consecutive) and removes the per-thread array entirely.
__global__ __launch_bounds__(256) void a1_conv_dw(
    const float* __restrict__ x, const float* __restrict__ w1,
    const float* __restrict__ w9, float* __restrict__ dwq,
    float* __restrict__ dwk, float* __restrict__ vout) {
  __shared__ float xs[C * 256];        // 48 KB: xs[ic*256 + halo_pos]
  __shared__ float qs[8 * 256];        // 8 KB staging: conv out, 8 ch/group
  const int t = threadIdx.x;
  const int bb = blockIdx.x / (NTX * NTY);
  const int tile = blockIdx.x % (NTX * NTY);
  const int ty = tile / NTX, tx = tile % NTX;

  // ---- phase 0: load x halo into LDS ----
  const int hyy = t / HSX, hxx = t % HSX;          // valid for t < 252
  const int hy = ty * TSY - 1 + hyy;
  const int hx = tx * TSX - 1 + hxx;
  const bool hin = (t < NHALO) && (hy >= 0) && (hy < H) && (hx >= 0) && (hx < W);
  const float* xb = x + (size_t)bb * C * HW + (hin ? (hy * W + hx) : 0);
#pragma unroll
  for (int ic = 0; ic < C; ++ic)
    xs[ic * 256 + t] = hin ? xb[(size_t)ic * HW] : 0.f;
  __syncthreads();

  // output pixel (threads 192..255 idle in dw phase); gx is 16-aligned
  const int py = t / TSX, px = t % TSX;
  const int gy = ty * TSY + py, gx = tx * TSX + px;
  const bool pin = (t < NPIX2) && (gy < H);
  const int hpos = py * HSX + px;                  // 3x3 window top-left

  for (int grp = 0; grp < 18; ++grp) {             // 8 output channels per group
    const int ch0 = grp * 8;
    const float* wp = w1 + ch0 * C;                // wave-uniform -> s_load
    float a[8];
#pragma unroll
    for (int g = 0; g < 8; ++g) a[g] = 0.f;
#pragma unroll
    for (int ic = 0; ic < C; ++ic) {
      const float xsv = xs[ic * 256 + t];
#pragma unroll
      for (int g = 0; g < 8; ++g) a[g] = fmaf(wp[g * C + ic], xsv, a[g]);
    }
#pragma unroll
    for (int g = 0; g < 8; ++g) qs[g * 256 + t] = a[g];
    __syncthreads();
    if (t < NPIX2) {
#pragma unroll
      for (int g = 0; g < 8; ++g) {
        const int ch = ch0 + g;
        const float* w9p = w9 + ch * 9;            // wave-uniform -> s_load
        const float* q = qs + g * 256 + hpos;
        float d = w9p[0] * q[0] + w9p[1] * q[1] + w9p[2] * q[2];
        d = fmaf(w9p[3], q[HSX], d);
        d = fmaf(w9p[4], q[HSX + 1], d);
        d = fmaf(w9p[5], q[HSX + 2], d);
        d = fmaf(w9p[6], q[2 * HSX], d);
        d = fmaf(w9p[7], q[2 * HSX + 1], d);
        d = fmaf(w9p[8], q[2 * HSX + 2], d);
        if (pin) {
          float* dst;
          int cc;
          if (ch < C)          { dst = dwq; cc = ch; }
          else if (ch < 2 * C) { dst = dwk; cc = ch - C; }
          else                 { dst = vout; cc = ch - 2 * C; }
          dst[((size_t)bb * C + cc) * HW + gy * W + gx] = d;
        }
      }
    }
    __syncthreads();   // qs reused next group
  }
}

// A2: per-chunk Gram partials + norm partials (no atomics).
__global__ __launch_bounds__(256) void a2_gram(
    const float* __restrict__ dwq, const float* __restrict__ dwk,
    float* __restrict__ Sp, float* __restrict__ nqp, float* __restrict__ nkp) {
  __shared__ float qs[C * 65];
  __shared__ float ks[C * 65];
  const int tid = threadIdx.x;
  const int bb = blockIdx.x / NCHUNK;
  const int chunk = blockIdx.x % NCHUNK;
  const int base = chunk * CHUNK;
  const float* qb = dwq + (size_t)bb * C * HW + base;
  const float* kb = dwk + (size_t)bb * C * HW + base;
  const int c0 = (tid >> 4) * 3;
  const int d0 = (tid & 15) * 3;
  float acc[3][3] = {{0.f}};
  float nacc = 0.f;
  for (int sub = 0; sub < CHUNK / 64; ++sub) {
    __syncthreads();
#pragma unroll
    for (int j = 0; j < 12; ++j) {
      const int idx = tid + j * 256;
      const int cc = idx >> 6;
      const int pp = idx & 63;
      qs[cc * 65 + pp] = qb[(size_t)cc * HW + sub * 64 + pp];
      ks[cc * 65 + pp] = kb[(size_t)cc * HW + sub * 64 + pp];
    }
    __syncthreads();
    if (tid < C) {
#pragma unroll
      for (int pp = 0; pp < 64; ++pp) { const float v = qs[tid * 65 + pp]; nacc = fmaf(v, v, nacc); }
    } else if (tid >= 64 && tid < 64 + C) {
      const int c = tid - 64;
#pragma unroll
      for (int pp = 0; pp < 64; ++pp) { const float v = ks[c * 65 + pp]; nacc = fmaf(v, v, nacc); }
    }
#pragma unroll 8
    for (int pp = 0; pp < 64; ++pp) {
      const float q0 = qs[(c0 + 0) * 65 + pp];
      const float q1 = qs[(c0 + 1) * 65 + pp];
      const float q2 = qs[(c0 + 2) * 65 + pp];
      const float k0 = ks[(d0 + 0) * 65 + pp];
      const float k1 = ks[(d0 + 1) * 65 + pp];
      const float k2 = ks[(d0 + 2) * 65 + pp];
      acc[0][0] = fmaf(q0, k0, acc[0][0]);
      acc[0][1] = fmaf(q0, k1, acc[0][1]);
      acc[0][2] = fmaf(q0, k2, acc[0][2]);
      acc[1][0] = fmaf(q1, k0, acc[1][0]);
      acc[1][1] = fmaf(q1, k1, acc[1][1]);
      acc[1][2] = fmaf(q1, k2, acc[1][2]);
      acc[2][0] = fmaf(q2, k0, acc[2][0]);
      acc[2][1] = fmaf(q2, k1, acc[2][1]);
      acc[2][2] = fmaf(q2, k2, acc[2][2]);
    }
  }
  float* Sb = Sp + ((size_t)bb * NCHUNK + chunk) * C * C;
#pragma unroll
  for (int i = 0; i < 3; ++i)
#pragma unroll
    for (int j = 0; j < 3; ++j)
      Sb[(c0 + i) * C + (d0 + j)] = acc[i][j];
  if (tid < C)                        nqp[((size_t)bb * NCHUNK + chunk) * C + tid] = nacc;
  else if (tid >= 64 && tid < 64 + C) nkp[((size_t)bb * NCHUNK + chunk) * C + (tid - 64)] = nacc;
}

// A3a: flat parallel reduction of the chunk partials (one thread per output).
#define RED_N (B * C * C + 2 * B * C)   // 9600
__global__ __launch_bounds__(256) void a3a_reduce(
    const float* __restrict__ Sp, const float* __restrict__ nqp,
    const float* __restrict__ nkp, float* __restrict__ S,
    float* __restrict__ nq, float* __restrict__ nk) {
  const int gid = blockIdx.x * 256 + threadIdx.x;
  if (gid < B * C * C) {
    const int bb = gid / (C * C), j = gid - bb * (C * C);
    const float* src = Sp + (size_t)bb * NCHUNK * C * C + j;
    float s = 0.f;
#pragma unroll 8
    for (int i = 0; i < NCHUNK; ++i) s += src[(size_t)i * C * C];
    S[gid] = s;
  } else if (gid < B * C * C + B * C) {
    const int r = gid - B * C * C;
    const int bb = r / C, j = r - bb * C;
    const float* src = nqp + (size_t)bb * NCHUNK * C + j;
    float s = 0.f;
#pragma unroll 8
    for (int i = 0; i < NCHUNK; ++i) s += src[(size_t)i * C];
    nq[r] = s;
  } else if (gid < RED_N) {
    const int r = gid - B * C * C - B * C;
    const int bb = r / C, j = r - bb * C;
    const float* src = nkp + (size_t)bb * NCHUNK * C + j;
    float s = 0.f;
#pragma unroll 8
    for (int i = 0; i < NCHUNK; ++i) s += src[(size_t)i * C];
    nk[r] = s;
  }
}

// A3b: normalize S by L2 norms, * temperature, row softmax, fold proj:
// M = proj_w @ attn. One block per batch. (nq/nk hold sums of squares.)
__global__ __launch_bounds__(64) void a3b_attn(
    const float* __restrict__ S, const float* __restrict__ nq,
    const float* __restrict__ nk, const float* __restrict__ proj_w,
    const float* __restrict__ temperature, float* __restrict__ M) {
  __shared__ float A[C * C];
  __shared__ float knl[C];
  const int bb = blockIdx.x;
  const int t = threadIdx.x;
  const float T = temperature[0];
  if (t < C) knl[t] = fmaxf(sqrtf(nk[bb * C + t]), EPSN);
  __syncthreads();
  if (t < C) {
    const float qn = fmaxf(sqrtf(nq[bb * C + t]), EPSN);
    float row[C];
    float m = -1e30f;
    for (int d = 0; d < C; ++d) {
      const float v = S[(size_t)bb * C * C + t * C + d] / (qn * knl[d]) * T;
      row[d] = v;
      m = fmaxf(m, v);
    }
    float sum = 0.f;
    for (int d = 0; d < C; ++d) { const float e = expf(row[d] - m); row[d] = e; sum += e; }
    const float inv = 1.f / sum;
    for (int d = 0; d < C; ++d) A[t * C + d] = row[d] * inv;
  }
  __syncthreads();
  for (int idx = t; idx < C * C; idx += 64) {
    const int e = idx / C, d = idx % C;
    float acc = 0.f;
    for (int cc = 0; cc < C; ++cc) acc = fmaf(proj_w[e * C + cc], A[cc * C + d], acc);
    M[(size_t)bb * C * C + idx] = acc;
  }
}

// A4: out[e,p] = sum_d M[e,d]*v[d,p], in place on d_out (v lives there).
// LDS-tiled: v-tile (48x64) + M in LDS; wave w computes e in [12w,12w+12) for
// 64 pixels. No per-thread 48-array => no spill (rounds 3-5 lesson).
__global__ __launch_bounds__(256) void a4_apply(
    float* __restrict__ out, const float* __restrict__ M) {
  __shared__ float vs[C * 64];   // 12 KB
  __shared__ float Ms[C * C];    // 9 KB
  const int t = threadIdx.x;
  const int bb = blockIdx.x >> 10;               // 1024 tiles per batch
  const int p0 = (blockIdx.x & 1023) << 6;       // 64 pixels per tile
  float* ob = out + (size_t)bb * C * HW + p0;
#pragma unroll
  for (int j = 0; j < 12; ++j) {                 // 48*64 = 3072 = 12*256
    const int idx = t + j * 256;
    const int d = idx >> 6, pl = idx & 63;
    vs[idx] = ob[(size_t)d * HW + pl];
  }
  for (int j = t; j < C * C; j += 256) Ms[j] = M[bb * C * C + j];
  __syncthreads();
  const int pl = t & 63;
  const int e0 = (t >> 6) * 12;                  // wave-uniform
  float acc[12];
#pragma unroll
  for (int j = 0; j < 12; ++j) acc[j] = 0.f;
  for (int d = 0; d < C; ++d) {
    const float vd = vs[d * 64 + pl];
#pragma unroll
    for (int j = 0; j < 12; ++j) acc[j] = fmaf(Ms[(e0 + j) * C + d], vd, acc[j]);
  }
#pragma unroll
  for (int j = 0; j < 12; ++j) ob[(size_t)(e0 + j) * HW + pl] = acc[j];
}

// ==================== PATH B (fallback) kernels ==============================

__global__ __launch_bounds__(256) void k0_zero(float* __restrict__ ws) {
  const int i = blockIdx.x * 256 + threadIdx.x;
  if (i < B_ZERO_N) ws[i] = 0.f;
}

#define TS 14
#define HS 16
#define NT 19
#define NPIX 196

__global__ __launch_bounds__(256) void k1_fused(
    const float* __restrict__ x, const float* __restrict__ w1,
    const float* __restrict__ w9, float* __restrict__ vout,
    float* __restrict__ S, float* __restrict__ nq, float* __restrict__ nk) {
  __shared__ float qs[4 * 256];
  __shared__ float qt[NPIX * C];
  __shared__ float kt[NPIX * C];
  const int t = threadIdx.x;
  const int bb = blockIdx.x / (NT * NT);
  const int tile = blockIdx.x % (NT * NT);
  const int ty = tile / NT, tx = tile % NT;
  const int hy = ty * TS - 1 + (t >> 4);
  const int hx = tx * TS - 1 + (t & 15);
  const bool hin = (hy >= 0 && hy < H && hx >= 0 && hx < W);
  const float* xb = x + (size_t)bb * C * HW;
  float xv[C];
#pragma unroll
  for (int ic = 0; ic < C; ++ic)
    xv[ic] = hin ? xb[(size_t)ic * HW + hy * W + hx] : 0.f;
  const int py = t / TS, px = t % TS;
  const int gy = ty * TS + py, gx = tx * TS + px;
  const bool pin = (t < NPIX) && (gy < H) && (gx < W);
  for (int grp = 0; grp < 36; ++grp) {
    const int ch0 = grp * 4;
    const float* wp = w1 + ch0 * C;
    float a0 = 0.f, a1 = 0.f, a2 = 0.f, a3 = 0.f;
#pragma unroll
    for (int ic = 0; ic < C; ++ic) {
      const float xs = xv[ic];
      a0 = fmaf(wp[ic], xs, a0);
      a1 = fmaf(wp[C + ic], xs, a1);
      a2 = fmaf(wp[2 * C + ic], xs, a2);
      a3 = fmaf(wp[3 * C + ic], xs, a3);
    }
    qs[0 * 256 + t] = a0;
    qs[1 * 256 + t] = a1;
    qs[2 * 256 + t] = a2;
    qs[3 * 256 + t] = a3;
    __syncthreads();
    if (t < NPIX) {
#pragma unroll
      for (int g = 0; g < 4; ++g) {
        const int ch = ch0 + g;
        const float* w9p = w9 + ch * 9;
        const float* q = qs + g * 256 + py * HS + px;
        float d = w9p[0] * q[0] + w9p[1] * q[1] + w9p[2] * q[2];
        d = fmaf(w9p[3], q[HS], d);
        d = fmaf(w9p[4], q[HS + 1], d);
        d = fmaf(w9p[5], q[HS + 2], d);
        d = fmaf(w9p[6], q[2 * HS], d);
        d = fmaf(w9p[7], q[2 * HS + 1], d);
        d = fmaf(w9p[8], q[2 * HS + 2], d);
        if (ch < C)          qt[t * C + ch] = pin ? d : 0.f;
        else if (ch < 2 * C) kt[t * C + (ch - C)] = pin ? d : 0.f;
        else if (pin)        vout[((size_t)bb * C + (ch - 2 * C)) * HW + gy * W + gx] = d;
      }
    }
    __syncthreads();
  }
  if (t < C) {
    float s = 0.f;
    for (int p = 0; p < NPIX; ++p) { const float v = qt[p * C + t]; s = fmaf(v, v, s); }
    atomicAdd(&nq[bb * C + t], s);
  } else if (t >= 64 && t < 64 + C) {
    const int c = t - 64;
    float s = 0.f;
    for (int p = 0; p < NPIX; ++p) { const float v = kt[p * C + c]; s = fmaf(v, v, s); }
    atomicAdd(&nk[bb * C + c], s);
  }
  {
    const int part = t >> 6;
    const int idx = t & 63;
    const int c0 = (idx >> 3) * 6;
    const int d0 = (idx & 7) * 6;
    float acc[6][6] = {{0.f}};
    const int p0 = part * 49;
    for (int p = p0; p < p0 + 49; ++p) {
      float qv[6], kv[6];
#pragma unroll
      for (int j = 0; j < 6; ++j) { qv[j] = qt[p * C + c0 + j]; kv[j] = kt[p * C + d0 + j]; }
#pragma unroll
      for (int i = 0; i < 6; ++i)
#pragma unroll
        for (int j = 0; j < 6; ++j) acc[i][j] = fmaf(qv[i], kv[j], acc[i][j]);
    }
    float* Sb = S + (size_t)bb * C * C;
#pragma unroll
    for (int i = 0; i < 6; ++i)
#pragma unroll
      for (int j = 0; j < 6; ++j) atomicAdd(&Sb[(c0 + i) * C + (d0 + j)], acc[i][j]);
  }
}

// =============================================================================

extern "C" void kernel_launch(void* const* d_in, const int* in_sizes, int n_in,
                              void* d_out, int out_size, void* d_ws, size_t ws_size,
                              hipStream_t stream) {
  const float* x      = (const float*)d_in[0];
  const float* qkv_w  = (const float*)d_in[1];
  const float* dw_w   = (const float*)d_in[2];
  const float* proj_w = (const float*)d_in[3];
  const float* temp   = (const float*)d_in[4];
  float* out = (float*)d_out;
  float* ws  = (float*)d_ws;

  if (ws_size >= A_FLOATS * sizeof(float)) {
    float* dwq = ws + A_DWQ_OFF;
    float* dwk = ws + A_DWK_OFF;
    float* Sp  = ws + A_SP_OFF;
    float* nqp = ws + A_NQP_OFF;
    float* nkp = ws + A_NKP_OFF;
    float* S   = ws + A_S_OFF;
    float* nq  = ws + A_NQ_OFF;
    float* nk  = ws + A_NK_OFF;
    float* M   = ws + A_M_OFF;
    a1_conv_dw<<<B * NTX * NTY, 256, 0, stream>>>(x, qkv_w, dw_w, dwq, dwk, out);
    a2_gram<<<B * NCHUNK, 256, 0, stream>>>(dwq, dwk, Sp, nqp, nkp);
    a3a_reduce<<<(RED_N + 255) / 256, 256, 0, stream>>>(Sp, nqp, nkp, S, nq, nk);
    a3b_attn<<<B, 64, 0, stream>>>(S, nq, nk, proj_w, temp, M);
    a4_apply<<<B * 1024, 256, 0, stream>>>(out, M);
  } else {
    float* S  = ws + B_S_OFF;
    float* nq = ws + B_NQ_OFF;
    float* nk = ws + B_NK_OFF;
    float* M  = ws + B_M_OFF;
    k0_zero<<<(B_ZERO_N + 255) / 256, 256, 0, stream>>>(ws);
    k1_fused<<<B * NT * NT, 256, 0, stream>>>(x, qkv_w, dw_w, out, S, nq, nk);
    a3b_attn<<<B, 64, 0, stream>>>(S, nq, nk, proj_w, temp, M);
    a4_apply<<<B * 1024, 256, 0, stream>>>(out, M);
  }
}

// Round 7
// 429.162 us; speedup vs baseline: 1.2234x; 1.2234x over previous
//
#include <hip/hip_runtime.h>

#define B 4
#define C 48
#define C3 144
#define H 256
#define W 256
#define HW 65536
#define EPSN 1e-12f

// ---- a1 tiling: 16x12 output tile, 18x14 halo (252 positions) ----
#define TSX 16
#define TSY 12
#define HSX 18
#define HSY 14
#define NTX 16           // 256/16
#define NTY 22           // ceil(256/12)
#define NPIX2 192        // TSX*TSY
#define NHALO 252        // HSX*HSY

#define NCHUNK 128       // gram chunks per batch
#define CHUNK 512        // pixels per gram chunk
#define LP 68            // padded LDS row stride for a2 (float4-aligned, <=2-way banks)

// ================= PATH A workspace layout (floats), ~106 MB =================
#define A_DWQ_OFF  ((size_t)0)
#define A_DWK_OFF  (A_DWQ_OFF + (size_t)B * C * HW)
#define A_SP_OFF   (A_DWK_OFF + (size_t)B * C * HW)            // B*128*2304
#define A_NQP_OFF  (A_SP_OFF + (size_t)B * NCHUNK * C * C)     // B*128*48
#define A_NKP_OFF  (A_NQP_OFF + (size_t)B * NCHUNK * C)
#define A_S_OFF    (A_NKP_OFF + (size_t)B * NCHUNK * C)        // B*2304
#define A_NQ_OFF   (A_S_OFF + (size_t)B * C * C)               // B*48
#define A_NK_OFF   (A_NQ_OFF + (size_t)B * C)
#define A_M_OFF    (A_NK_OFF + (size_t)B * C)                  // B*2304
#define A_FLOATS   (A_M_OFF + (size_t)B * C * C)

// ================= PATH B (fallback) workspace layout, ~75 KB ================
#define B_S_OFF  0
#define B_NQ_OFF (B * C * C)
#define B_NK_OFF (B_NQ_OFF + B * C)
#define B_M_OFF  (B_NK_OFF + B * C)
#define B_ZERO_N (B * C * C + 2 * B * C)

// ============================ PATH A kernels =================================

// A1: 1x1 conv + depthwise 3x3. One block per (batch, 16x12 tile).
// Round-6 post-mortem: the inner loop's 8 stride-48 weights forced 8 scalar
// s_load_dword per ic (≈1 SMEM per FMA, lgkmcnt storms, VALUBusy 26%). Fix:
// stage transposed w1T[ic][8] + w9 per group into LDS; read weights as
// wave-uniform ds_read_b128 broadcasts (free). x halo also in LDS (rounds 3-5:
// per-thread xv[48] always spills).
__global__ __launch_bounds__(256) void a1_conv_dw(
    const float* __restrict__ x, const float* __restrict__ w1,
    const float* __restrict__ w9, float* __restrict__ dwq,
    float* __restrict__ dwk, float* __restrict__ vout) {
  __shared__ float xs[C * 256];        // 48 KB: xs[ic*256 + halo_pos]
  __shared__ float qs[8 * 256];        // 8 KB: conv out staging, 8 ch/group
  __shared__ float wg[C * 8];          // 1.5 KB: w1T[ic][g] for this group
  __shared__ float wg9[8 * 9];         // 288 B: w9 for this group
  const int t = threadIdx.x;
  const int bb = blockIdx.x / (NTX * NTY);
  const int tile = blockIdx.x % (NTX * NTY);
  const int ty = tile / NTX, tx = tile % NTX;

  // ---- phase 0: load x halo into LDS ----
  const int hyy = t / HSX, hxx = t % HSX;          // valid for t < 252
  const int hy = ty * TSY - 1 + hyy;
  const int hx = tx * TSX - 1 + hxx;
  const bool hin = (t < NHALO) && (hy >= 0) && (hy < H) && (hx >= 0) && (hx < W);
  const float* xb = x + (size_t)bb * C * HW + (hin ? (hy * W + hx) : 0);
#pragma unroll
  for (int ic = 0; ic < C; ++ic)
    xs[ic * 256 + t] = hin ? xb[(size_t)ic * HW] : 0.f;

  // output pixel (threads 192..255 idle in dw phase); gx is 16-aligned
  const int py = t / TSX, px = t % TSX;
  const int gy = ty * TSY + py, gx = tx * TSX + px;
  const bool pin = (t < NPIX2) && (gy < H);
  const int hpos = py * HSX + px;                  // 3x3 window top-left

  for (int grp = 0; grp < 18; ++grp) {             // 8 output channels per group
    const int ch0 = grp * 8;
    // ---- stage this group's weights (transposed) ----
    {
      const int j = t + ((t < 128) ? 256 : 0);     // threads 0..127 do 2 elems
      if (t < 128) {
        const int ic = t >> 3, g = t & 7;
        wg[t] = w1[(ch0 + g) * C + ic];
        const int ic2 = j >> 3, g2 = j & 7;
        wg[j] = w1[(ch0 + g2) * C + ic2];
      } else if (t < 256) {
        const int r = t - 128;                     // 128..255 -> 128..255
        const int ic = (r + 128) >> 3, g = (r + 128) & 7;
        wg[r + 128] = w1[(ch0 + g) * C + ic];
      }
      if (t < 72) wg9[t] = w9[ch0 * 9 + t];        // contiguous, coalesced
    }
    __syncthreads();                               // wg/wg9 (and xs on grp 0) ready

    float a[8];
#pragma unroll
    for (int g = 0; g < 8; ++g) a[g] = 0.f;
#pragma unroll 4
    for (int ic = 0; ic < C; ++ic) {
      const float xsv = xs[ic * 256 + t];
      const float4 w0 = *(const float4*)&wg[ic * 8];      // wave-uniform addr
      const float4 w4 = *(const float4*)&wg[ic * 8 + 4];  // -> LDS broadcast
      a[0] = fmaf(w0.x, xsv, a[0]);
      a[1] = fmaf(w0.y, xsv, a[1]);
      a[2] = fmaf(w0.z, xsv, a[2]);
      a[3] = fmaf(w0.w, xsv, a[3]);
      a[4] = fmaf(w4.x, xsv, a[4]);
      a[5] = fmaf(w4.y, xsv, a[5]);
      a[6] = fmaf(w4.z, xsv, a[6]);
      a[7] = fmaf(w4.w, xsv, a[7]);
    }
#pragma unroll
    for (int g = 0; g < 8; ++g) qs[g * 256 + t] = a[g];
    __syncthreads();
    if (t < NPIX2) {
#pragma unroll
      for (int g = 0; g < 8; ++g) {
        const int ch = ch0 + g;
        const float* w9p = wg9 + g * 9;            // wave-uniform -> broadcast
        const float* q = qs + g * 256 + hpos;
        float d = w9p[0] * q[0] + w9p[1] * q[1] + w9p[2] * q[2];
        d = fmaf(w9p[3], q[HSX], d);
        d = fmaf(w9p[4], q[HSX + 1], d);
        d = fmaf(w9p[5], q[HSX + 2], d);
        d = fmaf(w9p[6], q[2 * HSX], d);
        d = fmaf(w9p[7], q[2 * HSX + 1], d);
        d = fmaf(w9p[8], q[2 * HSX + 2], d);
        if (pin) {
          float* dst;
          int cc;
          if (ch < C)          { dst = dwq; cc = ch; }
          else if (ch < 2 * C) { dst = dwk; cc = ch - C; }
          else                 { dst = vout; cc = ch - 2 * C; }
          dst[((size_t)bb * C + cc) * HW + gy * W + gx] = d;
        }
      }
    }
    __syncthreads();   // qs/wg reused next group
  }
}

// A2: per-chunk Gram partials + norm partials (no atomics). 512 blocks (2/CU).
__global__ __launch_bounds__(256) void a2_gram(
    const float* __restrict__ dwq, const float* __restrict__ dwk,
    float* __restrict__ Sp, float* __restrict__ nqp, float* __restrict__ nkp) {
  __shared__ float qs[C * LP];
  __shared__ float ks[C * LP];
  const int tid = threadIdx.x;
  const int bb = blockIdx.x / NCHUNK;
  const int chunk = blockIdx.x % NCHUNK;
  const int base = chunk * CHUNK;
  const float* qb = dwq + (size_t)bb * C * HW + base;
  const float* kb = dwk + (size_t)bb * C * HW + base;
  const int c0 = (tid >> 4) * 3;
  const int d0 = (tid & 15) * 3;
  float acc[3][3] = {{0.f}};
  float nacc = 0.f;
  for (int sub = 0; sub < CHUNK / 64; ++sub) {
    __syncthreads();
#pragma unroll
    for (int j = 0; j < 3; ++j) {                 // 768 float4 = 48x64
      const int f = tid + j * 256;
      const int cc = f >> 4, p4 = (f & 15) * 4;
      *(float4*)&qs[cc * LP + p4] = *(const float4*)&qb[(size_t)cc * HW + sub * 64 + p4];
      *(float4*)&ks[cc * LP + p4] = *(const float4*)&kb[(size_t)cc * HW + sub * 64 + p4];
    }
    __syncthreads();
    if (tid < C) {
#pragma unroll
      for (int pp = 0; pp < 64; ++pp) { const float v = qs[tid * LP + pp]; nacc = fmaf(v, v, nacc); }
    } else if (tid >= 64 && tid < 64 + C) {
      const int c = tid - 64;
#pragma unroll
      for (int pp = 0; pp < 64; ++pp) { const float v = ks[c * LP + pp]; nacc = fmaf(v, v, nacc); }
    }
#pragma unroll 8
    for (int pp = 0; pp < 64; ++pp) {
      const float q0 = qs[(c0 + 0) * LP + pp];
      const float q1 = qs[(c0 + 1) * LP + pp];
      const float q2 = qs[(c0 + 2) * LP + pp];
      const float k0 = ks[(d0 + 0) * LP + pp];
      const float k1 = ks[(d0 + 1) * LP + pp];
      const float k2 = ks[(d0 + 2) * LP + pp];
      acc[0][0] = fmaf(q0, k0, acc[0][0]);
      acc[0][1] = fmaf(q0, k1, acc[0][1]);
      acc[0][2] = fmaf(q0, k2, acc[0][2]);
      acc[1][0] = fmaf(q1, k0, acc[1][0]);
      acc[1][1] = fmaf(q1, k1, acc[1][1]);
      acc[1][2] = fmaf(q1, k2, acc[1][2]);
      acc[2][0] = fmaf(q2, k0, acc[2][0]);
      acc[2][1] = fmaf(q2, k1, acc[2][1]);
      acc[2][2] = fmaf(q2, k2, acc[2][2]);
    }
  }
  float* Sb = Sp + ((size_t)bb * NCHUNK + chunk) * C * C;
#pragma unroll
  for (int i = 0; i < 3; ++i)
#pragma unroll
    for (int j = 0; j < 3; ++j)
      Sb[(c0 + i) * C + (d0 + j)] = acc[i][j];
  if (tid < C)                        nqp[((size_t)bb * NCHUNK + chunk) * C + tid] = nacc;
  else if (tid >= 64 && tid < 64 + C) nkp[((size_t)bb * NCHUNK + chunk) * C + (tid - 64)] = nacc;
}

// A3a: flat parallel reduction of the chunk partials (one thread per output).
#define RED_N (B * C * C + 2 * B * C)   // 9600
__global__ __launch_bounds__(256) void a3a_reduce(
    const float* __restrict__ Sp, const float* __restrict__ nqp,
    const float* __restrict__ nkp, float* __restrict__ S,
    float* __restrict__ nq, float* __restrict__ nk) {
  const int gid = blockIdx.x * 256 + threadIdx.x;
  if (gid < B * C * C) {
    const int bb = gid / (C * C), j = gid - bb * (C * C);
    const float* src = Sp + (size_t)bb * NCHUNK * C * C + j;
    float s = 0.f;
#pragma unroll 8
    for (int i = 0; i < NCHUNK; ++i) s += src[(size_t)i * C * C];
    S[gid] = s;
  } else if (gid < B * C * C + B * C) {
    const int r = gid - B * C * C;
    const int bb = r / C, j = r - bb * C;
    const float* src = nqp + (size_t)bb * NCHUNK * C + j;
    float s = 0.f;
#pragma unroll 8
    for (int i = 0; i < NCHUNK; ++i) s += src[(size_t)i * C];
    nq[r] = s;
  } else if (gid < RED_N) {
    const int r = gid - B * C * C - B * C;
    const int bb = r / C, j = r - bb * C;
    const float* src = nkp + (size_t)bb * NCHUNK * C + j;
    float s = 0.f;
#pragma unroll 8
    for (int i = 0; i < NCHUNK; ++i) s += src[(size_t)i * C];
    nk[r] = s;
  }
}

// A3b: normalize S by L2 norms, * temperature, row softmax, fold proj:
// M = proj_w @ attn. One block per batch. (nq/nk hold sums of squares.)
__global__ __launch_bounds__(64) void a3b_attn(
    const float* __restrict__ S, const float* __restrict__ nq,
    const float* __restrict__ nk, const float* __restrict__ proj_w,
    const float* __restrict__ temperature, float* __restrict__ M) {
  __shared__ float A[C * C];
  __shared__ float knl[C];
  const int bb = blockIdx.x;
  const int t = threadIdx.x;
  const float T = temperature[0];
  if (t < C) knl[t] = fmaxf(sqrtf(nk[bb * C + t]), EPSN);
  __syncthreads();
  if (t < C) {
    const float qn = fmaxf(sqrtf(nq[bb * C + t]), EPSN);
    float row[C];
    float m = -1e30f;
    for (int d = 0; d < C; ++d) {
      const float v = S[(size_t)bb * C * C + t * C + d] / (qn * knl[d]) * T;
      row[d] = v;
      m = fmaxf(m, v);
    }
    float sum = 0.f;
    for (int d = 0; d < C; ++d) { const float e = expf(row[d] - m); row[d] = e; sum += e; }
    const float inv = 1.f / sum;
    for (int d = 0; d < C; ++d) A[t * C + d] = row[d] * inv;
  }
  __syncthreads();
  for (int idx = t; idx < C * C; idx += 64) {
    const int e = idx / C, d = idx % C;
    float acc = 0.f;
    for (int cc = 0; cc < C; ++cc) acc = fmaf(proj_w[e * C + cc], A[cc * C + d], acc);
    M[(size_t)bb * C * C + idx] = acc;
  }
}

// A4: out[e,p] = sum_d M[e,d]*v[d,p], in place on d_out (v lives there).
// LDS-tiled: v-tile (48x64) + M in LDS; wave w computes e in [12w,12w+12).
__global__ __launch_bounds__(256) void a4_apply(
    float* __restrict__ out, const float* __restrict__ M) {
  __shared__ float vs[C * 64];   // 12 KB
  __shared__ float Ms[C * C];    // 9 KB
  const int t = threadIdx.x;
  const int bb = blockIdx.x >> 10;               // 1024 tiles per batch
  const int p0 = (blockIdx.x & 1023) << 6;       // 64 pixels per tile
  float* ob = out + (size_t)bb * C * HW + p0;
#pragma unroll
  for (int j = 0; j < 3; ++j) {                  // 768 float4 = 48x64
    const int f = t + j * 256;
    const int d = f >> 4, p4 = (f & 15) * 4;
    *(float4*)&vs[d * 64 + p4] = *(const float4*)&ob[(size_t)d * HW + p4];
  }
  for (int j = t; j < C * C; j += 256) Ms[j] = M[bb * C * C + j];
  __syncthreads();
  const int pl = t & 63;
  const int e0 = (t >> 6) * 12;                  // wave-uniform
  float acc[12];
#pragma unroll
  for (int j = 0; j < 12; ++j) acc[j] = 0.f;
  for (int d = 0; d < C; ++d) {
    const float vd = vs[d * 64 + pl];
#pragma unroll
    for (int j = 0; j < 12; ++j) acc[j] = fmaf(Ms[(e0 + j) * C + d], vd, acc[j]);
  }
#pragma unroll
  for (int j = 0; j < 12; ++j) ob[(size_t)(e0 + j) * HW + pl] = acc[j];
}

// ==================== PATH B (fallback) kernels ==============================

__global__ __launch_bounds__(256) void k0_zero(float* __restrict__ ws) {
  const int i = blockIdx.x * 256 + threadIdx.x;
  if (i < B_ZERO_N) ws[i] = 0.f;
}

#define TS 14
#define HS 16
#define NT 19
#define NPIX 196

__global__ __launch_bounds__(256) void k1_fused(
    const float* __restrict__ x, const float* __restrict__ w1,
    const float* __restrict__ w9, float* __restrict__ vout,
    float* __restrict__ S, float* __restrict__ nq, float* __restrict__ nk) {
  __shared__ float qs[4 * 256];
  __shared__ float qt[NPIX * C];
  __shared__ float kt[NPIX * C];
  const int t = threadIdx.x;
  const int bb = blockIdx.x / (NT * NT);
  const int tile = blockIdx.x % (NT * NT);
  const int ty = tile / NT, tx = tile % NT;
  const int hy = ty * TS - 1 + (t >> 4);
  const int hx = tx * TS - 1 + (t & 15);
  const bool hin = (hy >= 0 && hy < H && hx >= 0 && hx < W);
  const float* xb = x + (size_t)bb * C * HW;
  float xv[C];
#pragma unroll
  for (int ic = 0; ic < C; ++ic)
    xv[ic] = hin ? xb[(size_t)ic * HW + hy * W + hx] : 0.f;
  const int py = t / TS, px = t % TS;
  const int gy = ty * TS + py, gx = tx * TS + px;
  const bool pin = (t < NPIX) && (gy < H) && (gx < W);
  for (int grp = 0; grp < 36; ++grp) {
    const int ch0 = grp * 4;
    const float* wp = w1 + ch0 * C;
    float a0 = 0.f, a1 = 0.f, a2 = 0.f, a3 = 0.f;
#pragma unroll
    for (int ic = 0; ic < C; ++ic) {
      const float xs = xv[ic];
      a0 = fmaf(wp[ic], xs, a0);
      a1 = fmaf(wp[C + ic], xs, a1);
      a2 = fmaf(wp[2 * C + ic], xs, a2);
      a3 = fmaf(wp[3 * C + ic], xs, a3);
    }
    qs[0 * 256 + t] = a0;
    qs[1 * 256 + t] = a1;
    qs[2 * 256 + t] = a2;
    qs[3 * 256 + t] = a3;
    __syncthreads();
    if (t < NPIX) {
#pragma unroll
      for (int g = 0; g < 4; ++g) {
        const int ch = ch0 + g;
        const float* w9p = w9 + ch * 9;
        const float* q = qs + g * 256 + py * HS + px;
        float d = w9p[0] * q[0] + w9p[1] * q[1] + w9p[2] * q[2];
        d = fmaf(w9p[3], q[HS], d);
        d = fmaf(w9p[4], q[HS + 1], d);
        d = fmaf(w9p[5], q[HS + 2], d);
        d = fmaf(w9p[6], q[2 * HS], d);
        d = fmaf(w9p[7], q[2 * HS + 1], d);
        d = fmaf(w9p[8], q[2 * HS + 2], d);
        if (ch < C)          qt[t * C + ch] = pin ? d : 0.f;
        else if (ch < 2 * C) kt[t * C + (ch - C)] = pin ? d : 0.f;
        else if (pin)        vout[((size_t)bb * C + (ch - 2 * C)) * HW + gy * W + gx] = d;
      }
    }
    __syncthreads();
  }
  if (t < C) {
    float s = 0.f;
    for (int p = 0; p < NPIX; ++p) { const float v = qt[p * C + t]; s = fmaf(v, v, s); }
    atomicAdd(&nq[bb * C + t], s);
  } else if (t >= 64 && t < 64 + C) {
    const int c = t - 64;
    float s = 0.f;
    for (int p = 0; p < NPIX; ++p) { const float v = kt[p * C + c]; s = fmaf(v, v, s); }
    atomicAdd(&nk[bb * C + c], s);
  }
  {
    const int part = t >> 6;
    const int idx = t & 63;
    const int c0 = (idx >> 3) * 6;
    const int d0 = (idx & 7) * 6;
    float acc[6][6] = {{0.f}};
    const int p0 = part * 49;
    for (int p = p0; p < p0 + 49; ++p) {
      float qv[6], kv[6];
#pragma unroll
      for (int j = 0; j < 6; ++j) { qv[j] = qt[p * C + c0 + j]; kv[j] = kt[p * C + d0 + j]; }
#pragma unroll
      for (int i = 0; i < 6; ++i)
#pragma unroll
        for (int j = 0; j < 6; ++j) acc[i][j] = fmaf(qv[i], kv[j], acc[i][j]);
    }
    float* Sb = S + (size_t)bb * C * C;
#pragma unroll
    for (int i = 0; i < 6; ++i)
#pragma unroll
      for (int j = 0; j < 6; ++j) atomicAdd(&Sb[(c0 + i) * C + (d0 + j)], acc[i][j]);
  }
}

// =============================================================================

extern "C" void kernel_launch(void* const* d_in, const int* in_sizes, int n_in,
                              void* d_out, int out_size, void* d_ws, size_t ws_size,
                              hipStream_t stream) {
  const float* x      = (const float*)d_in[0];
  const float* qkv_w  = (const float*)d_in[1];
  const float* dw_w   = (const float*)d_in[2];
  const float* proj_w = (const float*)d_in[3];
  const float* temp   = (const float*)d_in[4];
  float* out = (float*)d_out;
  float* ws  = (float*)d_ws;

  if (ws_size >= A_FLOATS * sizeof(float)) {
    float* dwq = ws + A_DWQ_OFF;
    float* dwk = ws + A_DWK_OFF;
    float* Sp  = ws + A_SP_OFF;
    float* nqp = ws + A_NQP_OFF;
    float* nkp = ws + A_NKP_OFF;
    float* S   = ws + A_S_OFF;
    float* nq  = ws + A_NQ_OFF;
    float* nk  = ws + A_NK_OFF;
    float* M   = ws + A_M_OFF;
    a1_conv_dw<<<B * NTX * NTY, 256, 0, stream>>>(x, qkv_w, dw_w, dwq, dwk, out);
    a2_gram<<<B * NCHUNK, 256, 0, stream>>>(dwq, dwk, Sp, nqp, nkp);
    a3a_reduce<<<(RED_N + 255) / 256, 256, 0, stream>>>(Sp, nqp, nkp, S, nq, nk);
    a3b_attn<<<B, 64, 0, stream>>>(S, nq, nk, proj_w, temp, M);
    a4_apply<<<B * 1024, 256, 0, stream>>>(out, M);
  } else {
    float* S  = ws + B_S_OFF;
    float* nq = ws + B_NQ_OFF;
    float* nk = ws + B_NK_OFF;
    float* M  = ws + B_M_OFF;
    k0_zero<<<(B_ZERO_N + 255) / 256, 256, 0, stream>>>(ws);
    k1_fused<<<B * NT * NT, 256, 0, stream>>>(x, qkv_w, dw_w, out, S, nq, nk);
    a3b_attn<<<B, 64, 0, stream>>>(S, nq, nk, proj_w, temp, M);
    a4_apply<<<B * 1024, 256, 0, stream>>>(out, M);
  }
}